// Round 10
// baseline (333.687 us; speedup 1.0000x reference)
//
#include <hip/hip_runtime.h>

#define CI 64
#define CO 128
#define HH 64
#define WW 64
#define OH 62
#define OW 62
#define XTW 66          // xT padded row width: 64 real cols + 2 zero cols

typedef __attribute__((ext_vector_type(8))) short short8x;
typedef __attribute__((ext_vector_type(16))) float f32x16;

// Weight scratch + pre-transposed input in module device-globals (not d_ws);
// both fully rewritten every launch (idempotent, graph-capture safe).
__device__ __attribute__((aligned(16))) ushort g_wt[9 * CO * CI];          // [tap][co][ci] bf16
__device__ __attribute__((aligned(16))) ushort g_xt[64 * 64 * XTW * 64];   // [b][h][w(66)][ci] bf16

__device__ __forceinline__ ushort bf16rne(float f) {
    unsigned u = __builtin_bit_cast(unsigned, f);
    u += 0x7fffu + ((u >> 16) & 1u);
    return (ushort)(u >> 16);
}

__global__ __launch_bounds__(256)
void wprep(const float* __restrict__ w) {
    const int idx = blockIdx.x * 256 + threadIdx.x;   // 73728 total
    const int kk = idx >> 13;
    const int rem = idx & 8191;
    const int co = rem >> 6, ci = rem & 63;
    g_wt[idx] = bf16rne(w[(co * 64 + ci) * 9 + kk]);
}

// NCHW f32 -> [b][h][w+pad][ci] bf16 via LDS tile transpose.  (proven r2/r7)
__global__ __launch_bounds__(256)
void xprep(const float* __restrict__ x) {
    __shared__ ushort T[64 * 68];                     // [ci][w + pad4], 8.7 KB
    const int t = threadIdx.x;
    const int h = blockIdx.x, b = blockIdx.y;
    const float* xb = x + ((size_t)b * 64 * 64 + h) * 64;   // + ci*4096 + w

    #pragma unroll
    for (int g = 0; g < 4; ++g) {
        const int ci = g * 16 + (t >> 4);
        const int w0 = (t & 15) * 4;
        const float4 v = *(const float4*)(xb + (size_t)ci * 4096 + w0);
        ushort tmp[4];
        tmp[0] = bf16rne(v.x); tmp[1] = bf16rne(v.y);
        tmp[2] = bf16rne(v.z); tmp[3] = bf16rne(v.w);
        *reinterpret_cast<uint2*>(&T[ci * 68 + w0]) = *reinterpret_cast<const uint2*>(tmp);
    }
    __syncthreads();

    ushort* dst = g_xt + (size_t)(b * 64 + h) * XTW * 64;
    #pragma unroll
    for (int g = 0; g < 2; ++g) {
        const int w = g * 32 + (t >> 3);
        const int cg = t & 7;
        ushort tmp[8];
        #pragma unroll
        for (int j = 0; j < 8; ++j) tmp[j] = T[(cg * 8 + j) * 68 + w];
        *reinterpret_cast<uint4*>(dst + w * 64 + cg * 8) = *reinterpret_cast<const uint4*>(tmp);
    }
    if (t < 16) {   // zero the 2 pad columns (px 64,65): 256 B
        const uint4 z{0, 0, 0, 0};
        *reinterpret_cast<uint4*>(dst + 64 * 64 + t * 8) = z;
    }
}

// Barrier-free conv: 256 threads (4 waves = co-half x 2 rows), 2 output rows
// per block, grid 31x64 = 1984 blocks.  NO input LDS, NO staging, NO
// recurring barrier: B-fragments are read straight from g_xt (already in
// exact MFMA B layout; L1/L2-served -- per tap a wave's 8 loads fully
// consume 32 x 128 B regions, taps overlap 31/32 in L1).  Rationale: every
// phased structure (r0/r7/r9) pinned at 1.6-2.0 TB/s because clone-blocks
// barrier into lockstep phases (store pipe fed ~30% of the time); the
// harness fill at 5.2 TB/s proves continuously-issuing waves saturate.
// Here every wave free-runs load->MFMA->store; blocks retire and refill
// continuously -> statistically mixed phases, all pipes fed.
__global__ __launch_bounds__(256, 2)
void conv_fused(const float* __restrict__ bias, float* __restrict__ out) {
    __shared__ float sB[CO];   // 512 B -- the only LDS

    const int tid = threadIdx.x;
    const int wv = tid >> 6, L = tid & 63, l31 = L & 31, q = L >> 5;
    const int h = wv >> 1;           // co half: co base = h*64
    const int rw = wv & 1;           // output row (0/1)
    const int b = blockIdx.y, oh0 = blockIdx.x * 2;

    if (tid < CO) sB[tid] = bias[tid];
    __syncthreads();   // one-time, at block start (bias); no recurring phases

    // ---- tap-0 A-fragment loads (verified layout: m=l31, k=q*8+j) ----
    const ushort* wbase = g_wt + (h * 64 + l31) * 64 + q * 8;
    short8x wbuf[2][8];   // [dbuf][m*4+s]
    #pragma unroll
    for (int m = 0; m < 2; ++m)
        #pragma unroll
        for (int ss = 0; ss < 4; ++ss)
            wbuf[0][m * 4 + ss] = *(const short8x*)(wbase + m * 2048 + ss * 16);

    // input row base for this wave (kr=0): g_xt[b][oh0+rw][.][.]
    const ushort* xrow = g_xt + (size_t)((b * 64 + oh0 + rw) * XTW) * 64;

    f32x16 acc[2][2];
    #pragma unroll
    for (int i = 0; i < 2; ++i)
        #pragma unroll
        for (int jj = 0; jj < 2; ++jj)
            #pragma unroll
            for (int r = 0; r < 16; ++r) acc[i][jj][r] = 0.f;

    // ---- K-loop: 9 taps, A double-buffered in regs, B direct from global ----
    #pragma unroll
    for (int kk = 0; kk < 9; ++kk) {
        const short8x* wf = wbuf[kk & 1];
        if (kk < 8) {   // prefetch next tap's A while this tap computes
            const ushort* nb = wbase + (kk + 1) * (CO * CI);
            #pragma unroll
            for (int m = 0; m < 2; ++m)
                #pragma unroll
                for (int ss = 0; ss < 4; ++ss)
                    wbuf[(kk + 1) & 1][m * 4 + ss] = *(const short8x*)(nb + m * 2048 + ss * 16);
        }
        const int kr = kk / 3, kc = kk - kr * 3;
        // pixel (row oh0+rw+kr, col kc+l31); col <= 2+31+32 = 65 (pad cols
        // 64/65 are zero-filled by xprep -> no masking needed)
        const ushort* bP0 = xrow + (size_t)(kr * XTW + kc + l31) * 64;
        #pragma unroll
        for (int ss = 0; ss < 4; ++ss) {
            const int ob = (ss * 2 + q) * 8;          // plain layout, no swizzle
            short8x b0 = *(const short8x*)(bP0 + ob);
            short8x b1 = *(const short8x*)(bP0 + 32 * 64 + ob);
            acc[0][0] = __builtin_amdgcn_mfma_f32_32x32x16_bf16(wf[ss],     b0, acc[0][0], 0, 0, 0);
            acc[0][1] = __builtin_amdgcn_mfma_f32_32x32x16_bf16(wf[ss],     b1, acc[0][1], 0, 0, 0);
            acc[1][0] = __builtin_amdgcn_mfma_f32_32x32x16_bf16(wf[4 + ss], b0, acc[1][0], 0, 0, 0);
            acc[1][1] = __builtin_amdgcn_mfma_f32_32x32x16_bf16(wf[4 + ss], b1, acc[1][1], 0, 0, 0);
        }
    }

    // ---- terminal epilogue (verified r0 mapping) ----
    const int oh = oh0 + rw;   // <= 61, always valid (grid covers exactly 62)
    #pragma unroll
    for (int mt = 0; mt < 2; ++mt)
        #pragma unroll
        for (int nt = 0; nt < 2; ++nt) {
            const int col = nt * 32 + l31;
            if (col < OW) {
                #pragma unroll
                for (int reg = 0; reg < 16; ++reg) {
                    const int co = h * 64 + mt * 32 + 4 * q + (reg & 3) + 8 * (reg >> 2);
                    out[(((size_t)b * CO + co) * OH + oh) * OW + col] = acc[mt][nt][reg] + sB[co];
                }
            }
        }
}

extern "C" void kernel_launch(void* const* d_in, const int* in_sizes, int n_in,
                              void* d_out, int out_size, void* d_ws, size_t ws_size,
                              hipStream_t stream) {
    const float* x    = (const float*)d_in[0];
    const float* wgt  = (const float*)d_in[1];
    const float* bias = (const float*)d_in[2];
    float* out = (float*)d_out;

    wprep<<<dim3(288), 256, 0, stream>>>(wgt);
    xprep<<<dim3(64, 64), 256, 0, stream>>>(x);
    conv_fused<<<dim3(31, 64), 256, 0, stream>>>(bias, out);
}

// Round 11
// 258.077 us; speedup vs baseline: 1.2930x; 1.2930x over previous
//
#include <hip/hip_runtime.h>

#define CI 64
#define CO 128
#define HH 64
#define WW 64
#define OH 62
#define OW 62
#define XTW 66          // xT padded row width: 64 real cols + 2 zero cols
#define RB (XTW * 64)   // ushorts per staged input row = 4224 (8448 B)
#define ROWS_OUT 4      // output rows per block (2 per wave)
#define ROWS_IN 6       // staged input rows per block
#define NBLK_X 16       // ceil(62/4); last block masks oh>=62

typedef __attribute__((ext_vector_type(8))) short short8x;
typedef __attribute__((ext_vector_type(16))) float f32x16;

// Weight scratch + pre-transposed input in module device-globals (not d_ws);
// both fully rewritten every launch (idempotent, graph-capture safe).
__device__ __attribute__((aligned(16))) ushort g_wt[9 * CO * CI];          // [tap][co][ci] bf16
__device__ __attribute__((aligned(16))) ushort g_xt[64 * 64 * XTW * 64];   // [b][h][w(66)][ci] bf16

__device__ __forceinline__ ushort bf16rne(float f) {
    unsigned u = __builtin_bit_cast(unsigned, f);
    u += 0x7fffu + ((u >> 16) & 1u);
    return (ushort)(u >> 16);
}

__device__ __forceinline__ void gld_lds16(const ushort* g, ushort* l) {
    __builtin_amdgcn_global_load_lds(
        (const __attribute__((address_space(1))) unsigned*)g,
        (__attribute__((address_space(3))) unsigned*)l, 16, 0, 0);
}

__global__ __launch_bounds__(256)
void wprep(const float* __restrict__ w) {
    const int idx = blockIdx.x * 256 + threadIdx.x;   // 73728 total
    const int kk = idx >> 13;
    const int rem = idx & 8191;
    const int co = rem >> 6, ci = rem & 63;
    g_wt[idx] = bf16rne(w[(co * 64 + ci) * 9 + kk]);
}

// NCHW f32 -> [b][h][w+pad][ci] bf16 via LDS tile transpose.  (proven r2/r7)
__global__ __launch_bounds__(256)
void xprep(const float* __restrict__ x) {
    __shared__ ushort T[64 * 68];                     // [ci][w + pad4], 8.7 KB
    const int t = threadIdx.x;
    const int h = blockIdx.x, b = blockIdx.y;
    const float* xb = x + ((size_t)b * 64 * 64 + h) * 64;   // + ci*4096 + w

    #pragma unroll
    for (int g = 0; g < 4; ++g) {
        const int ci = g * 16 + (t >> 4);
        const int w0 = (t & 15) * 4;
        const float4 v = *(const float4*)(xb + (size_t)ci * 4096 + w0);
        ushort tmp[4];
        tmp[0] = bf16rne(v.x); tmp[1] = bf16rne(v.y);
        tmp[2] = bf16rne(v.z); tmp[3] = bf16rne(v.w);
        *reinterpret_cast<uint2*>(&T[ci * 68 + w0]) = *reinterpret_cast<const uint2*>(tmp);
    }
    __syncthreads();

    ushort* dst = g_xt + (size_t)(b * 64 + h) * XTW * 64;
    #pragma unroll
    for (int g = 0; g < 2; ++g) {
        const int w = g * 32 + (t >> 3);
        const int cg = t & 7;
        ushort tmp[8];
        #pragma unroll
        for (int j = 0; j < 8; ++j) tmp[j] = T[(cg * 8 + j) * 68 + w];
        *reinterpret_cast<uint4*>(dst + w * 64 + cg * 8) = *reinterpret_cast<const uint4*>(tmp);
    }
    if (t < 16) {   // zero the 2 pad columns (px 64,65): 256 B
        const uint4 z{0, 0, 0, 0};
        *reinterpret_cast<uint4*>(dst + 64 * 64 + t * 8) = z;
    }
}

// r7 skeleton with 2 output rows PER WAVE: 256 threads (4 waves = co-half x
// rw), wave (h,rw) computes rows oh0+rw and oh0+rw+2 -> per tap the SAME 8
// A-fragment loads feed 32 MFMAs instead of 16.  Rationale: the invariant
// cost across r0/r7/r9/r10 is per-tap weight re-reads through the per-CU
// TCP/L1 (64 B/cy): 576 KB/block, ~590 MB chip-wide ~= the 100 us floor.
// This halves weight traffic per output and doubles the MFMA run per tap
// (A-prefetch latency fully hidden).  Everything else is r7-verified:
// 6-row stage via gload_lds (src-swizzled, linear dest), ONE barrier,
// tap-prefetch A double-buffer, terminal epilogue.
__global__ __launch_bounds__(256, 2)
void conv_fused(const float* __restrict__ bias, float* __restrict__ out) {
    __shared__ ushort Xl[ROWS_IN * RB];   // 50,688 B
    __shared__ float  sB[CO];

    const int tid = threadIdx.x;
    const int wv = tid >> 6, L = tid & 63, l31 = L & 31, q = L >> 5;
    const int h = wv >> 1;           // co half: co base = h*64
    const int rw = wv & 1;           // wave's first row; second = rw+2
    const int b = blockIdx.y, oh0 = blockIdx.x * ROWS_OUT;

    if (tid < CO) sB[tid] = bias[tid];

    // ---- tap-0 A-fragment loads first (verified layout: m=l31, k=q*8+j) ----
    const ushort* wbase = g_wt + (h * 64 + l31) * 64 + q * 8;
    short8x wbuf[2][8];   // [dbuf][m*4+s]
    #pragma unroll
    for (int m = 0; m < 2; ++m)
        #pragma unroll
        for (int ss = 0; ss < 4; ++ss)
            wbuf[0][m * 4 + ss] = *(const short8x*)(wbase + m * 2048 + ss * 16);

    // ---- stage 6 input rows: 3168 16B-chunks via gload_lds, src-swizzled ----
    // Chunk i -> LDS byte i*16 (linear; wave dest = uniform base + lane*16).
    // Physical LDS pixel pl = i>>3; swizzle key = pl&7 (matches read f0).
    const ushort* xb = g_xt + (size_t)(b * 64) * RB;
    #pragma unroll
    for (int j = 0; j < 12; ++j) {
        const int i = j * 256 + tid;
        const int pl = i >> 3, c = i & 7;
        const int r6 = pl / 66;                  // staged row 0..5
        const int px = pl - r6 * 66;
        int ir = oh0 + r6;                       // input image row
        if (ir > 63) ir = 63;                    // last strip clamp (in-bounds)
        gld_lds16(xb + (size_t)ir * RB + px * 64 + ((c ^ (pl & 7)) * 8),
                  &Xl[(size_t)(j * 256 + (tid & 192)) * 8]);
    }
    if (tid < 96) {                              // tail chunks 3072..3167
        const int i = 3072 + tid;
        const int pl = i >> 3, c = i & 7;
        const int r6 = pl / 66;
        const int px = pl - r6 * 66;
        int ir = oh0 + r6;
        if (ir > 63) ir = 63;
        gld_lds16(xb + (size_t)ir * RB + px * 64 + ((c ^ (pl & 7)) * 8),
                  &Xl[(size_t)(3072 + (tid & 192)) * 8]);
    }

    f32x16 acc[2][2][2];   // [row2][mt][nt] -- 128 VGPRs
    #pragma unroll
    for (int r2 = 0; r2 < 2; ++r2)
        #pragma unroll
        for (int i = 0; i < 2; ++i)
            #pragma unroll
            for (int jj = 0; jj < 2; ++jj)
                #pragma unroll
                for (int r = 0; r < 16; ++r) acc[r2][i][jj][r] = 0.f;

    __syncthreads();   // the only barrier (drains gload_lds + wbuf loads)

    // ---- K-loop: 9 taps; per tap 8 A-loads feed BOTH rows (32 MFMAs) ----
    #pragma unroll
    for (int kk = 0; kk < 9; ++kk) {
        const short8x* wf = wbuf[kk & 1];
        if (kk < 8) {   // prefetch next tap's A while this tap computes
            const ushort* nb = wbase + (kk + 1) * (CO * CI);
            #pragma unroll
            for (int m = 0; m < 2; ++m)
                #pragma unroll
                for (int ss = 0; ss < 4; ++ss)
                    wbuf[(kk + 1) & 1][m * 4 + ss] = *(const short8x*)(nb + m * 2048 + ss * 16);
        }
        const int kr = kk / 3, kc = kk - kr * 3;
        const int pBa = (rw + kr) * XTW + kc + l31;       // row rw
        const int pBb = (rw + 2 + kr) * XTW + kc + l31;   // row rw+2
        const ushort* bPa = Xl + pBa * 64;
        const ushort* bPb = Xl + pBb * 64;
        const int f0a = pBa & 7, f0b = pBb & 7;           // (pB+32)&7 == f0
        #pragma unroll
        for (int ss = 0; ss < 4; ++ss) {
            const int oba = (((ss * 2 + q) ^ f0a) * 8);
            const int obb = (((ss * 2 + q) ^ f0b) * 8);
            short8x a0 = *(const short8x*)(bPa + oba);
            short8x a1 = *(const short8x*)(bPa + 32 * 64 + oba);
            short8x c0 = *(const short8x*)(bPb + obb);
            short8x c1 = *(const short8x*)(bPb + 32 * 64 + obb);
            acc[0][0][0] = __builtin_amdgcn_mfma_f32_32x32x16_bf16(wf[ss],     a0, acc[0][0][0], 0, 0, 0);
            acc[0][0][1] = __builtin_amdgcn_mfma_f32_32x32x16_bf16(wf[ss],     a1, acc[0][0][1], 0, 0, 0);
            acc[0][1][0] = __builtin_amdgcn_mfma_f32_32x32x16_bf16(wf[4 + ss], a0, acc[0][1][0], 0, 0, 0);
            acc[0][1][1] = __builtin_amdgcn_mfma_f32_32x32x16_bf16(wf[4 + ss], a1, acc[0][1][1], 0, 0, 0);
            acc[1][0][0] = __builtin_amdgcn_mfma_f32_32x32x16_bf16(wf[ss],     c0, acc[1][0][0], 0, 0, 0);
            acc[1][0][1] = __builtin_amdgcn_mfma_f32_32x32x16_bf16(wf[ss],     c1, acc[1][0][1], 0, 0, 0);
            acc[1][1][0] = __builtin_amdgcn_mfma_f32_32x32x16_bf16(wf[4 + ss], c0, acc[1][1][0], 0, 0, 0);
            acc[1][1][1] = __builtin_amdgcn_mfma_f32_32x32x16_bf16(wf[4 + ss], c1, acc[1][1][1], 0, 0, 0);
        }
    }

    // ---- terminal epilogue (verified r0 mapping), both rows ----
    #pragma unroll
    for (int r2 = 0; r2 < 2; ++r2) {
        const int oh = oh0 + rw + 2 * r2;
        if (oh < OH) {
            #pragma unroll
            for (int mt = 0; mt < 2; ++mt)
                #pragma unroll
                for (int nt = 0; nt < 2; ++nt) {
                    const int col = nt * 32 + l31;
                    if (col < OW) {
                        #pragma unroll
                        for (int reg = 0; reg < 16; ++reg) {
                            const int co = h * 64 + mt * 32 + 4 * q + (reg & 3) + 8 * (reg >> 2);
                            out[(((size_t)b * CO + co) * OH + oh) * OW + col] = acc[r2][mt][nt][reg] + sB[co];
                        }
                    }
                }
        }
    }
}

extern "C" void kernel_launch(void* const* d_in, const int* in_sizes, int n_in,
                              void* d_out, int out_size, void* d_ws, size_t ws_size,
                              hipStream_t stream) {
    const float* x    = (const float*)d_in[0];
    const float* wgt  = (const float*)d_in[1];
    const float* bias = (const float*)d_in[2];
    float* out = (float*)d_out;

    wprep<<<dim3(288), 256, 0, stream>>>(wgt);
    xprep<<<dim3(64, 64), 256, 0, stream>>>(x);
    conv_fused<<<dim3(NBLK_X, 64), 256, 0, stream>>>(bias, out);
}

// Round 15
// 217.199 us; speedup vs baseline: 1.5363x; 1.1882x over previous
//
#include <hip/hip_runtime.h>

#define CI 64
#define CO 128
#define HH 64
#define WW 64
#define OH 62
#define OW 62
#define XTW 66          // padded row width in LDS: 64 real cols + 2 zero cols
#define RB (XTW * 64)   // ushorts per staged input row = 4224 (8448 B)
#define ROWS_OUT 4      // output rows per block (2 per wave)
#define ROWS_IN 6       // staged input rows per block
#define NBLK_X 16       // ceil(62/4); last block masks oh>=62

typedef __attribute__((ext_vector_type(8))) short short8x;
typedef __attribute__((ext_vector_type(16))) float f32x16;

// Weight scratch in a module device-global (not d_ws); wprep rewrites it
// every launch (idempotent, graph-capture safe).  ~3 us, L2-resident.
__device__ __attribute__((aligned(16))) ushort g_wt[9 * CO * CI];   // [tap][co][ci] bf16

__device__ __forceinline__ ushort bf16rne(float f) {
    unsigned u = __builtin_bit_cast(unsigned, f);
    u += 0x7fffu + ((u >> 16) & 1u);
    return (ushort)(u >> 16);
}

__global__ __launch_bounds__(256)
void wprep(const float* __restrict__ w) {
    const int idx = blockIdx.x * 256 + threadIdx.x;   // 73728 total
    const int kk = idx >> 13;
    const int rem = idx & 8191;
    const int co = rem >> 6, ci = rem & 63;
    g_wt[idx] = bf16rne(w[(co * 64 + ci) * 9 + kk]);
}

// Fused conv: r11's verified skeleton (256 thr, 4 waves = co-half x rw, 2
// output rows per wave, ONE barrier, tap-prefetch A double-buffer, terminal
// epilogue) with the NCHW->[px][ci] transpose fused back in -- COALESCED.
// Scoreboard rationale: conv gains (127->~90) were cancelled by xprep's
// ~35-40us pass; fusing removes the g_xt HBM round-trip (287->235 MB total)
// and one dispatch.  Staging scheme: thread t owns pixel w=t&63; wave wv
// owns ci 16*wv..16*wv+15.  Per row: 16 coalesced global_load_dword (each
// wave-instr = 256 B contiguous of x), cvt, pack two 8-ci groups, two
// ds_write_b128 into the swizzled slot (group ^ (pl&7)) at pixel pl --
// byte-identical LDS content to the r7/r11-verified layout, so the K-loop
// and epilogue are UNCHANGED.  b128 writes are conflict-free (64 lanes ->
// 64 distinct 16B slots; XOR key de-aliases the 128B row stride).
__global__ __launch_bounds__(256, 2)
void conv_fused(const float* __restrict__ x, const float* __restrict__ bias,
                float* __restrict__ out) {
    __shared__ ushort Xl[ROWS_IN * RB];   // 50,688 B
    __shared__ float  sB[CO];

    const int tid = threadIdx.x;
    const int wv = tid >> 6, L = tid & 63, l31 = L & 31, q = L >> 5;
    const int h = wv >> 1;           // co half: co base = h*64
    const int rw = wv & 1;           // wave's first row; second = rw+2
    const int b = blockIdx.y, oh0 = blockIdx.x * ROWS_OUT;

    if (tid < CO) sB[tid] = bias[tid];

    // ---- tap-0 A-fragment loads first (verified layout: m=l31, k=q*8+j) ----
    const ushort* wbase = g_wt + (h * 64 + l31) * 64 + q * 8;
    short8x wbuf[2][8];   // [dbuf][m*4+s]
    #pragma unroll
    for (int m = 0; m < 2; ++m)
        #pragma unroll
        for (int ss = 0; ss < 4; ++ss)
            wbuf[0][m * 4 + ss] = *(const short8x*)(wbase + m * 2048 + ss * 16);

    // ---- zero-pad pixels 64,65 of each staged row (96 x uint4) ----
    if (tid < 96) {
        const int r6 = tid >> 4, c = tid & 15;
        const int px = 64 + (c >> 3), slot = c & 7;
        const uint4 z{0, 0, 0, 0};
        *reinterpret_cast<uint4*>(&Xl[(r6 * XTW + px) * 64 + slot * 8]) = z;
    }

    // ---- stage 6 input rows: coalesced loads + in-register transpose ----
    // lane pixel w = L; wave ci-block = wv*16 + k (k=0..15).
    {
        const int w = L;
        const size_t cibase = (size_t)(b * 64 + wv * 16) * (HH * WW);
        #pragma unroll
        for (int r6 = 0; r6 < ROWS_IN; ++r6) {
            int ir = oh0 + r6;
            if (ir > 63) ir = 63;                 // last strip clamp (dummy)
            const float* src = x + cibase + (size_t)ir * WW + w;
            union { ushort u[8]; uint4 v; } p0, p1;
            #pragma unroll
            for (int k = 0; k < 8; ++k)
                p0.u[k] = bf16rne(src[(size_t)k * (HH * WW)]);
            #pragma unroll
            for (int k = 0; k < 8; ++k)
                p1.u[k] = bf16rne(src[(size_t)(8 + k) * (HH * WW)]);
            const int pl = r6 * XTW + w, key = pl & 7;
            ushort* dst = &Xl[pl * 64];
            *reinterpret_cast<uint4*>(dst + (((2 * wv)     ^ key) * 8)) = p0.v;
            *reinterpret_cast<uint4*>(dst + (((2 * wv + 1) ^ key) * 8)) = p1.v;
        }
    }

    f32x16 acc[2][2][2];   // [row2][mt][nt] -- 128 VGPRs
    #pragma unroll
    for (int r2 = 0; r2 < 2; ++r2)
        #pragma unroll
        for (int i = 0; i < 2; ++i)
            #pragma unroll
            for (int jj = 0; jj < 2; ++jj)
                #pragma unroll
                for (int r = 0; r < 16; ++r) acc[r2][i][jj][r] = 0.f;

    __syncthreads();   // the only barrier (drains ds_writes + wbuf loads)

    // ---- K-loop: 9 taps; per tap 8 A-loads feed BOTH rows (32 MFMAs) ----
    #pragma unroll
    for (int kk = 0; kk < 9; ++kk) {
        const short8x* wf = wbuf[kk & 1];
        if (kk < 8) {   // prefetch next tap's A while this tap computes
            const ushort* nb = wbase + (kk + 1) * (CO * CI);
            #pragma unroll
            for (int m = 0; m < 2; ++m)
                #pragma unroll
                for (int ss = 0; ss < 4; ++ss)
                    wbuf[(kk + 1) & 1][m * 4 + ss] = *(const short8x*)(nb + m * 2048 + ss * 16);
        }
        const int kr = kk / 3, kc = kk - kr * 3;
        const int pBa = (rw + kr) * XTW + kc + l31;       // row rw
        const int pBb = (rw + 2 + kr) * XTW + kc + l31;   // row rw+2
        const ushort* bPa = Xl + pBa * 64;
        const ushort* bPb = Xl + pBb * 64;
        const int f0a = pBa & 7, f0b = pBb & 7;           // (pB+32)&7 == f0
        #pragma unroll
        for (int ss = 0; ss < 4; ++ss) {
            const int oba = (((ss * 2 + q) ^ f0a) * 8);
            const int obb = (((ss * 2 + q) ^ f0b) * 8);
            short8x a0 = *(const short8x*)(bPa + oba);
            short8x a1 = *(const short8x*)(bPa + 32 * 64 + oba);
            short8x c0 = *(const short8x*)(bPb + obb);
            short8x c1 = *(const short8x*)(bPb + 32 * 64 + obb);
            acc[0][0][0] = __builtin_amdgcn_mfma_f32_32x32x16_bf16(wf[ss],     a0, acc[0][0][0], 0, 0, 0);
            acc[0][0][1] = __builtin_amdgcn_mfma_f32_32x32x16_bf16(wf[ss],     a1, acc[0][0][1], 0, 0, 0);
            acc[0][1][0] = __builtin_amdgcn_mfma_f32_32x32x16_bf16(wf[4 + ss], a0, acc[0][1][0], 0, 0, 0);
            acc[0][1][1] = __builtin_amdgcn_mfma_f32_32x32x16_bf16(wf[4 + ss], a1, acc[0][1][1], 0, 0, 0);
            acc[1][0][0] = __builtin_amdgcn_mfma_f32_32x32x16_bf16(wf[ss],     c0, acc[1][0][0], 0, 0, 0);
            acc[1][0][1] = __builtin_amdgcn_mfma_f32_32x32x16_bf16(wf[ss],     c1, acc[1][0][1], 0, 0, 0);
            acc[1][1][0] = __builtin_amdgcn_mfma_f32_32x32x16_bf16(wf[4 + ss], c0, acc[1][1][0], 0, 0, 0);
            acc[1][1][1] = __builtin_amdgcn_mfma_f32_32x32x16_bf16(wf[4 + ss], c1, acc[1][1][1], 0, 0, 0);
        }
    }

    // ---- terminal epilogue (verified r0 mapping), both rows ----
    #pragma unroll
    for (int r2 = 0; r2 < 2; ++r2) {
        const int oh = oh0 + rw + 2 * r2;
        if (oh < OH) {
            #pragma unroll
            for (int mt = 0; mt < 2; ++mt)
                #pragma unroll
                for (int nt = 0; nt < 2; ++nt) {
                    const int col = nt * 32 + l31;
                    if (col < OW) {
                        #pragma unroll
                        for (int reg = 0; reg < 16; ++reg) {
                            const int co = h * 64 + mt * 32 + 4 * q + (reg & 3) + 8 * (reg >> 2);
                            out[(((size_t)b * CO + co) * OH + oh) * OW + col] = acc[r2][mt][nt][reg] + sB[co];
                        }
                    }
                }
        }
    }
}

extern "C" void kernel_launch(void* const* d_in, const int* in_sizes, int n_in,
                              void* d_out, int out_size, void* d_ws, size_t ws_size,
                              hipStream_t stream) {
    const float* x    = (const float*)d_in[0];
    const float* wgt  = (const float*)d_in[1];
    const float* bias = (const float*)d_in[2];
    float* out = (float*)d_out;

    wprep<<<dim3(288), 256, 0, stream>>>(wgt);
    conv_fused<<<dim3(NBLK_X, 64), 256, 0, stream>>>(x, bias, out);
}

// Round 16
// 214.861 us; speedup vs baseline: 1.5530x; 1.0109x over previous
//
#include <hip/hip_runtime.h>

#define CI 64
#define CO 128
#define HH 64
#define WW 64
#define OH 62
#define OW 62
#define XTW 66          // padded row width in LDS: 64 real cols + 2 zero cols
#define RB (XTW * 64)   // ushorts per staged input row = 4224 (8448 B)
#define ROWS_OUT 4      // output rows per block (2 per wave)
#define ROWS_IN 6       // staged input rows per block
#define NBLK_X 16       // ceil(62/4); last block masks oh>=62

typedef __attribute__((ext_vector_type(8))) short short8x;
typedef __attribute__((ext_vector_type(16))) float f32x16;

// Weight scratch in a module device-global (not d_ws); wprep rewrites it
// every launch (idempotent, graph-capture safe).  ~3 us, L2-resident.
__device__ __attribute__((aligned(16))) ushort g_wt[9 * CO * CI];   // [tap][co][ci] bf16

__device__ __forceinline__ ushort bf16rne(float f) {
    unsigned u = __builtin_bit_cast(unsigned, f);
    u += 0x7fffu + ((u >> 16) & 1u);
    return (ushort)(u >> 16);
}

__global__ __launch_bounds__(256)
void wprep(const float* __restrict__ w) {
    const int idx = blockIdx.x * 256 + threadIdx.x;   // 73728 total
    const int kk = idx >> 13;
    const int rem = idx & 8191;
    const int co = rem >> 6, ci = rem & 63;
    g_wt[idx] = bf16rne(w[(co * 64 + ci) * 9 + kk]);
}

// r15 winner (fused coalesced transpose-staging, 2 rows/wave, one-shot
// 4-row tile) + 2-PHASE staging: rows 0-3 staged before barrier 1; rows
// 4-5's 32 global loads issued BEFORE taps kr=0 (which need only rows
// 0-3), their ~900cy HBM latency hiding under ~2000cy of MFMA+ds_read;
// cvt+ds_write after taps 0-2, barrier 2, taps 3-8.  Rationale: r15 is
// register-capped at 2 waves/SIMD (128 VGPR + 128 AGPR acc) so TLP can't
// rise; the remaining stall is exposed stage latency -> overlap it
// within the wave.  All staging/swizzle/K-loop/epilogue patterns are
// byte-identical to the r15-verified kernel.
__global__ __launch_bounds__(256, 2)
void conv_fused(const float* __restrict__ x, const float* __restrict__ bias,
                float* __restrict__ out) {
    __shared__ ushort Xl[ROWS_IN * RB];   // 50,688 B
    __shared__ float  sB[CO];

    const int tid = threadIdx.x;
    const int wv = tid >> 6, L = tid & 63, l31 = L & 31, q = L >> 5;
    const int h = wv >> 1;           // co half: co base = h*64
    const int rw = wv & 1;           // wave's first row; second = rw+2
    const int b = blockIdx.y, oh0 = blockIdx.x * ROWS_OUT;

    if (tid < CO) sB[tid] = bias[tid];

    // ---- tap-0 A-fragment loads first (verified layout: m=l31, k=q*8+j) ----
    const ushort* wbase = g_wt + (h * 64 + l31) * 64 + q * 8;
    short8x wbuf[2][8];   // [dbuf][m*4+s]
    #pragma unroll
    for (int m = 0; m < 2; ++m)
        #pragma unroll
        for (int ss = 0; ss < 4; ++ss)
            wbuf[0][m * 4 + ss] = *(const short8x*)(wbase + m * 2048 + ss * 16);

    // ---- zero-pad pixels 64,65 of ALL 6 staged rows (96 x uint4) ----
    if (tid < 96) {
        const int r6 = tid >> 4, c = tid & 15;
        const int px = 64 + (c >> 3), slot = c & 7;
        const uint4 z{0, 0, 0, 0};
        *reinterpret_cast<uint4*>(&Xl[(r6 * XTW + px) * 64 + slot * 8]) = z;
    }

    // ---- phase 1: stage rows 0..3 (coalesced loads + in-reg transpose) ----
    // lane pixel w = L; wave ci-block = wv*16 + k (k=0..15).
    const int w = L;
    const size_t cibase = (size_t)(b * 64 + wv * 16) * (HH * WW);
    #pragma unroll
    for (int r6 = 0; r6 < 4; ++r6) {
        const int ir = oh0 + r6;                  // <= 63 (oh0 <= 60)
        const float* src = x + cibase + (size_t)ir * WW + w;
        union { ushort u[8]; uint4 v; } p0, p1;
        #pragma unroll
        for (int k = 0; k < 8; ++k)
            p0.u[k] = bf16rne(src[(size_t)k * (HH * WW)]);
        #pragma unroll
        for (int k = 0; k < 8; ++k)
            p1.u[k] = bf16rne(src[(size_t)(8 + k) * (HH * WW)]);
        const int pl = r6 * XTW + w, key = pl & 7;
        ushort* dst = &Xl[pl * 64];
        *reinterpret_cast<uint4*>(dst + (((2 * wv)     ^ key) * 8)) = p0.v;
        *reinterpret_cast<uint4*>(dst + (((2 * wv + 1) ^ key) * 8)) = p1.v;
    }

    f32x16 acc[2][2][2];   // [row2][mt][nt] -- 128 AGPRs
    #pragma unroll
    for (int r2 = 0; r2 < 2; ++r2)
        #pragma unroll
        for (int i = 0; i < 2; ++i)
            #pragma unroll
            for (int jj = 0; jj < 2; ++jj)
                #pragma unroll
                for (int r = 0; r < 16; ++r) acc[r2][i][jj][r] = 0.f;

    __syncthreads();   // barrier 1: rows 0..3 + pads visible

    // ---- issue rows 4,5 loads NOW (latency hides under taps kr=0) ----
    float v45[2][16];
    #pragma unroll
    for (int r2 = 0; r2 < 2; ++r2) {
        int ir = oh0 + 4 + r2;
        if (ir > 63) ir = 63;                     // last strip clamp (dummy)
        const float* src = x + cibase + (size_t)ir * WW + w;
        #pragma unroll
        for (int k = 0; k < 16; ++k)
            v45[r2][k] = src[(size_t)k * (HH * WW)];
    }

    // ---- taps kr=0 (kk=0..2): rows rw, rw+2 -- staged in phase 1 ----
    #pragma unroll
    for (int kk = 0; kk < 3; ++kk) {
        const short8x* wf = wbuf[kk & 1];
        {   // prefetch next tap's A
            const ushort* nb = wbase + (kk + 1) * (CO * CI);
            #pragma unroll
            for (int m = 0; m < 2; ++m)
                #pragma unroll
                for (int ss = 0; ss < 4; ++ss)
                    wbuf[(kk + 1) & 1][m * 4 + ss] = *(const short8x*)(nb + m * 2048 + ss * 16);
        }
        const int kc = kk;
        const int pBa = rw * XTW + kc + l31;              // row rw
        const int pBb = (rw + 2) * XTW + kc + l31;        // row rw+2
        const ushort* bPa = Xl + pBa * 64;
        const ushort* bPb = Xl + pBb * 64;
        const int f0a = pBa & 7, f0b = pBb & 7;
        #pragma unroll
        for (int ss = 0; ss < 4; ++ss) {
            const int oba = (((ss * 2 + q) ^ f0a) * 8);
            const int obb = (((ss * 2 + q) ^ f0b) * 8);
            short8x a0 = *(const short8x*)(bPa + oba);
            short8x a1 = *(const short8x*)(bPa + 32 * 64 + oba);
            short8x c0 = *(const short8x*)(bPb + obb);
            short8x c1 = *(const short8x*)(bPb + 32 * 64 + obb);
            acc[0][0][0] = __builtin_amdgcn_mfma_f32_32x32x16_bf16(wf[ss],     a0, acc[0][0][0], 0, 0, 0);
            acc[0][0][1] = __builtin_amdgcn_mfma_f32_32x32x16_bf16(wf[ss],     a1, acc[0][0][1], 0, 0, 0);
            acc[0][1][0] = __builtin_amdgcn_mfma_f32_32x32x16_bf16(wf[4 + ss], a0, acc[0][1][0], 0, 0, 0);
            acc[0][1][1] = __builtin_amdgcn_mfma_f32_32x32x16_bf16(wf[4 + ss], a1, acc[0][1][1], 0, 0, 0);
            acc[1][0][0] = __builtin_amdgcn_mfma_f32_32x32x16_bf16(wf[ss],     c0, acc[1][0][0], 0, 0, 0);
            acc[1][0][1] = __builtin_amdgcn_mfma_f32_32x32x16_bf16(wf[ss],     c1, acc[1][0][1], 0, 0, 0);
            acc[1][1][0] = __builtin_amdgcn_mfma_f32_32x32x16_bf16(wf[4 + ss], c0, acc[1][1][0], 0, 0, 0);
            acc[1][1][1] = __builtin_amdgcn_mfma_f32_32x32x16_bf16(wf[4 + ss], c1, acc[1][1][1], 0, 0, 0);
        }
    }

    // ---- cvt + ds_write rows 4,5 (loads have drained under the taps) ----
    #pragma unroll
    for (int r2 = 0; r2 < 2; ++r2) {
        union { ushort u[8]; uint4 v; } p0, p1;
        #pragma unroll
        for (int k = 0; k < 8; ++k) p0.u[k] = bf16rne(v45[r2][k]);
        #pragma unroll
        for (int k = 0; k < 8; ++k) p1.u[k] = bf16rne(v45[r2][8 + k]);
        const int pl = (4 + r2) * XTW + w, key = pl & 7;
        ushort* dst = &Xl[pl * 64];
        *reinterpret_cast<uint4*>(dst + (((2 * wv)     ^ key) * 8)) = p0.v;
        *reinterpret_cast<uint4*>(dst + (((2 * wv + 1) ^ key) * 8)) = p1.v;
    }

    __syncthreads();   // barrier 2: rows 4,5 visible

    // ---- taps kk=3..8 (kr=1,2) ----
    #pragma unroll
    for (int kk = 3; kk < 9; ++kk) {
        const short8x* wf = wbuf[kk & 1];
        if (kk < 8) {   // prefetch next tap's A
            const ushort* nb = wbase + (kk + 1) * (CO * CI);
            #pragma unroll
            for (int m = 0; m < 2; ++m)
                #pragma unroll
                for (int ss = 0; ss < 4; ++ss)
                    wbuf[(kk + 1) & 1][m * 4 + ss] = *(const short8x*)(nb + m * 2048 + ss * 16);
        }
        const int kr = kk / 3, kc = kk - kr * 3;
        const int pBa = (rw + kr) * XTW + kc + l31;       // row rw
        const int pBb = (rw + 2 + kr) * XTW + kc + l31;   // row rw+2
        const ushort* bPa = Xl + pBa * 64;
        const ushort* bPb = Xl + pBb * 64;
        const int f0a = pBa & 7, f0b = pBb & 7;
        #pragma unroll
        for (int ss = 0; ss < 4; ++ss) {
            const int oba = (((ss * 2 + q) ^ f0a) * 8);
            const int obb = (((ss * 2 + q) ^ f0b) * 8);
            short8x a0 = *(const short8x*)(bPa + oba);
            short8x a1 = *(const short8x*)(bPa + 32 * 64 + oba);
            short8x c0 = *(const short8x*)(bPb + obb);
            short8x c1 = *(const short8x*)(bPb + 32 * 64 + obb);
            acc[0][0][0] = __builtin_amdgcn_mfma_f32_32x32x16_bf16(wf[ss],     a0, acc[0][0][0], 0, 0, 0);
            acc[0][0][1] = __builtin_amdgcn_mfma_f32_32x32x16_bf16(wf[ss],     a1, acc[0][0][1], 0, 0, 0);
            acc[0][1][0] = __builtin_amdgcn_mfma_f32_32x32x16_bf16(wf[4 + ss], a0, acc[0][1][0], 0, 0, 0);
            acc[0][1][1] = __builtin_amdgcn_mfma_f32_32x32x16_bf16(wf[4 + ss], a1, acc[0][1][1], 0, 0, 0);
            acc[1][0][0] = __builtin_amdgcn_mfma_f32_32x32x16_bf16(wf[ss],     c0, acc[1][0][0], 0, 0, 0);
            acc[1][0][1] = __builtin_amdgcn_mfma_f32_32x32x16_bf16(wf[ss],     c1, acc[1][0][1], 0, 0, 0);
            acc[1][1][0] = __builtin_amdgcn_mfma_f32_32x32x16_bf16(wf[4 + ss], c0, acc[1][1][0], 0, 0, 0);
            acc[1][1][1] = __builtin_amdgcn_mfma_f32_32x32x16_bf16(wf[4 + ss], c1, acc[1][1][1], 0, 0, 0);
        }
    }

    // ---- terminal epilogue (verified r0 mapping), both rows ----
    #pragma unroll
    for (int r2 = 0; r2 < 2; ++r2) {
        const int oh = oh0 + rw + 2 * r2;
        if (oh < OH) {
            #pragma unroll
            for (int mt = 0; mt < 2; ++mt)
                #pragma unroll
                for (int nt = 0; nt < 2; ++nt) {
                    const int col = nt * 32 + l31;
                    if (col < OW) {
                        #pragma unroll
                        for (int reg = 0; reg < 16; ++reg) {
                            const int co = h * 64 + mt * 32 + 4 * q + (reg & 3) + 8 * (reg >> 2);
                            out[(((size_t)b * CO + co) * OH + oh) * OW + col] = acc[r2][mt][nt][reg] + sB[co];
                        }
                    }
                }
        }
    }
}

extern "C" void kernel_launch(void* const* d_in, const int* in_sizes, int n_in,
                              void* d_out, int out_size, void* d_ws, size_t ws_size,
                              hipStream_t stream) {
    const float* x    = (const float*)d_in[0];
    const float* wgt  = (const float*)d_in[1];
    const float* bias = (const float*)d_in[2];
    float* out = (float*)d_out;

    wprep<<<dim3(288), 256, 0, stream>>>(wgt);
    conv_fused<<<dim3(NBLK_X, 64), 256, 0, stream>>>(x, bias, out);
}